// Round 10
// baseline (3969.353 us; speedup 1.0000x reference)
//
#include <hip/hip_runtime.h>
#include <math.h>

// Round 10 (= R9 resubmit; R9 bench was an infra failure, kernel never ran).
// Fuse K2's r-gate half and K3 (A@rh) into one kernel via transposed in-block
// chaining: rh^T panel = sigma(Wzr_r^T @ AH^T + ...) ⊙ h^T computed per-block
// into LDS, then ARH = A @ rh^T directly. 4 -> 3 dispatches per super-step
// (262 -> 197 total). z-blocks / K1 / K4 keep verified code paths.

#define BB 8
#define TT 64
#define NN 256
#define HH 256
#define BN 2048
#define LSTR 72   // LDS row stride in ushorts for a 64-wide K chunk

typedef float f32x4 __attribute__((ext_vector_type(4)));
typedef short s16x8 __attribute__((ext_vector_type(8)));

#define MFMA(a, b, c) __builtin_amdgcn_mfma_f32_16x16x32_bf16(a, b, c, 0, 0, 0)

__device__ __forceinline__ ushort rne_bf16(float x) {
    unsigned u = __builtin_bit_cast(unsigned, x);
    unsigned r = u + 0x7FFFu + ((u >> 16) & 1u);
    return (ushort)(r >> 16);
}
__device__ __forceinline__ float bf16_f32(ushort h) {
    unsigned u = ((unsigned)h) << 16;
    return __builtin_bit_cast(float, u);
}
__device__ __forceinline__ void split2(float x, ushort& hi, ushort& lo) {
    ushort h = rne_bf16(x);
    hi = h;
    lo = rne_bf16(x - bf16_f32(h));
}

// ---------------------------------------------------------------------------
// prep: round A to bf16; build transposed bf16 weight slabs [Ncols][256]
// ---------------------------------------------------------------------------
__global__ __launch_bounds__(256) void prep_kernel(const float* __restrict__ A,
    const float* __restrict__ Wh0, const float* __restrict__ Wx1,
    const float* __restrict__ Wh1,
    ushort* Abf, ushort* WzrT0, ushort* WcT0, ushort* WxzrT1,
    ushort* WhzrT1, ushort* WxcT1, ushort* WhcT1)
{
    int idx = blockIdx.x * 256 + threadIdx.x;
    if (idx < 65536) { Abf[idx] = rne_bf16(A[idx]); return; }
    int e = idx - 65536;
    ushort* dst; const float* src; int colOff;
    if      (e < 131072) { dst = WzrT0;  src = Wh0; colOff = 0;   }
    else if (e < 196608) { dst = WcT0;   src = Wh0; colOff = 512; e -= 131072; }
    else if (e < 327680) { dst = WxzrT1; src = Wx1; colOff = 0;   e -= 196608; }
    else if (e < 458752) { dst = WhzrT1; src = Wh1; colOff = 0;   e -= 327680; }
    else if (e < 524288) { dst = WxcT1;  src = Wx1; colOff = 512; e -= 458752; }
    else if (e < 589824) { dst = WhcT1;  src = Wh1; colOff = 512; e -= 524288; }
    else return;
    int c = e >> 8, k = e & 255;
    dst[e] = rne_bf16(src[k * 768 + colOff + c]);
}

// ---------------------------------------------------------------------------
// x-job (exact fp32 Ax0 = A@(x_t*mask)) and head
// ---------------------------------------------------------------------------
__device__ void x_job(int lb, int tid, float* xs, float* red, const float* Af,
                      const float* x2d, const float* mask, float* Ax0, int t) {
    int b = lb >> 2, rt = lb & 3;
    const float* xbase = x2d + ((size_t)(b * TT + t) * NN) * 6;
    const float* mbase = mask + (size_t)(b * TT + t) * NN;
    {
        int m = tid;
        float mk = mbase[m];
        #pragma unroll
        for (int d = 0; d < 6; ++d) xs[m * 8 + d] = xbase[m * 6 + d] * mk;
    }
    __syncthreads();
    int i = tid & 63, q = tid >> 6;
    const float* arow = Af + (size_t)(rt * 64 + i) * 256 + q * 64;
    float a6[6] = {0.f, 0.f, 0.f, 0.f, 0.f, 0.f};
    for (int m = 0; m < 64; ++m) {
        float a = arow[m];
        const float* xv = &xs[(q * 64 + m) * 8];
        #pragma unroll
        for (int d = 0; d < 6; ++d) a6[d] = fmaf(a, xv[d], a6[d]);
    }
    #pragma unroll
    for (int d = 0; d < 6; ++d) red[(i * 4 + q) * 8 + d] = a6[d];
    __syncthreads();
    for (int idx2 = tid; idx2 < 64 * 6; idx2 += 256) {
        int ii = idx2 / 6, d = idx2 - ii * 6;
        float s = red[(ii * 4 + 0) * 8 + d] + red[(ii * 4 + 1) * 8 + d]
                + red[(ii * 4 + 2) * 8 + d] + red[(ii * 4 + 3) * 8 + d];
        Ax0[(size_t)(b * 256 + rt * 64 + ii) * 8 + d] = s;
    }
}

__device__ void head_job(int lb, int tid, const float* h1, const float* Wout,
                         const float* bout, float* out, int tprev) {
    int g = lb * 256 + tid;
    int row = g / 9, o = g - row * 9;
    if (row >= BN) return;
    const float* hr = h1 + (size_t)row * 256;
    float s = bout[o];
    for (int k = 0; k < 256; k += 4) {
        float4 hv = *(const float4*)(hr + k);
        s = fmaf(hv.x, Wout[(k + 0) * 9 + o], s);
        s = fmaf(hv.y, Wout[(k + 1) * 9 + o], s);
        s = fmaf(hv.z, Wout[(k + 2) * 9 + o], s);
        s = fmaf(hv.w, Wout[(k + 3) * 9 + o], s);
    }
    int b = row >> 8, n = row & 255;
    out[((size_t)(b * TT + tprev) * NN + n) * 9 + o] = s;
}

__global__ __launch_bounds__(256) void head_kernel(const float* __restrict__ h1,
    const float* __restrict__ Wout, const float* __restrict__ bout,
    float* __restrict__ out, int tprev)
{
    head_job(blockIdx.x, threadIdx.x, h1, Wout, bout, out, tprev);
}

// ---------------------------------------------------------------------------
// g2 (K1): AH = A_bf16 @ hT(hi+lo), register-prefetched staging (R8-verified)
// ---------------------------------------------------------------------------
struct G2P {
    const ushort* Abf;
    const ushort* XThi0; const ushort* XTlo0; ushort* Yhi0; ushort* Ylo0;
    const ushort* XThi1; const ushort* XTlo1; ushort* Yhi1; ushort* Ylo1;
    int nJobs;
    int doX;
    int headT;
    int t;
    const float* Af; const float* x2d; const float* mask; float* Ax0;
    const float* h1; const float* Wout; const float* bout; float* out;
};

__global__ __launch_bounds__(256) void g2_kernel(G2P p) {
    __shared__ ushort lds[3 * 64 * LSTR];
    ushort* As   = lds;
    ushort* Bshi = lds + 64 * LSTR;
    ushort* Bslo = lds + 2 * 64 * LSTR;
    const int tid = threadIdx.x;
    const int bid = blockIdx.x;
    const int mainB = p.nJobs * 128;

    if (bid < mainB) {
        const int job = bid >> 7, lb = bid & 127;
        const ushort* XThi = job ? p.XThi1 : p.XThi0;
        const ushort* XTlo = job ? p.XTlo1 : p.XTlo0;
        ushort* Yhi = job ? p.Yhi1 : p.Yhi0;
        ushort* Ylo = job ? p.Ylo1 : p.Ylo0;
        const int b = lb >> 4, rt = (lb >> 2) & 3, ct = lb & 3;

        const int lane = tid & 63, wave = tid >> 6;
        const int wr = wave >> 1, wc = wave & 1;
        const int l15 = lane & 15, q8 = (lane >> 4) << 3;

        f32x4 acc[2][2];
        acc[0][0] = 0.f; acc[0][1] = 0.f; acc[1][0] = 0.f; acc[1][1] = 0.f;

        const int rr = tid >> 2, ko = (tid & 3) << 4;
        const ushort* Asrc = p.Abf + (size_t)(rt * 64 + rr) * 256 + ko;
        const ushort* Bh   = XThi + (size_t)(b * 256 + ct * 64 + rr) * 256 + ko;
        const ushort* Bl   = XTlo + (size_t)(b * 256 + ct * 64 + rr) * 256 + ko;
        ushort* wA = &As[rr * LSTR + ko];
        ushort* wH = &Bshi[rr * LSTR + ko];
        ushort* wL = &Bslo[rr * LSTR + ko];

        uint4 rA0 = *(const uint4*)(Asrc);
        uint4 rA1 = *(const uint4*)(Asrc + 8);
        uint4 rH0 = *(const uint4*)(Bh);
        uint4 rH1 = *(const uint4*)(Bh + 8);
        uint4 rL0 = *(const uint4*)(Bl);
        uint4 rL1 = *(const uint4*)(Bl + 8);

        for (int k0 = 0; k0 < 256; k0 += 64) {
            __syncthreads();
            *(uint4*)(wA)     = rA0;
            *(uint4*)(wA + 8) = rA1;
            *(uint4*)(wH)     = rH0;
            *(uint4*)(wH + 8) = rH1;
            *(uint4*)(wL)     = rL0;
            *(uint4*)(wL + 8) = rL1;
            __syncthreads();
            if (k0 < 192) {
                rA0 = *(const uint4*)(Asrc + k0 + 64);
                rA1 = *(const uint4*)(Asrc + k0 + 72);
                rH0 = *(const uint4*)(Bh + k0 + 64);
                rH1 = *(const uint4*)(Bh + k0 + 72);
                rL0 = *(const uint4*)(Bl + k0 + 64);
                rL1 = *(const uint4*)(Bl + k0 + 72);
            }
            #pragma unroll
            for (int sub = 0; sub < 2; ++sub) {
                const int kb = sub * 32 + q8;
                s16x8 a0  = *(const s16x8*)&As[(wr * 32 + l15) * LSTR + kb];
                s16x8 a1  = *(const s16x8*)&As[(wr * 32 + 16 + l15) * LSTR + kb];
                s16x8 bh0 = *(const s16x8*)&Bshi[(wc * 32 + l15) * LSTR + kb];
                s16x8 bh1 = *(const s16x8*)&Bshi[(wc * 32 + 16 + l15) * LSTR + kb];
                s16x8 bl0 = *(const s16x8*)&Bslo[(wc * 32 + l15) * LSTR + kb];
                s16x8 bl1 = *(const s16x8*)&Bslo[(wc * 32 + 16 + l15) * LSTR + kb];
                acc[0][0] = MFMA(a0, bh0, acc[0][0]);
                acc[0][0] = MFMA(a0, bl0, acc[0][0]);
                acc[0][1] = MFMA(a0, bh1, acc[0][1]);
                acc[0][1] = MFMA(a0, bl1, acc[0][1]);
                acc[1][0] = MFMA(a1, bh0, acc[1][0]);
                acc[1][0] = MFMA(a1, bl0, acc[1][0]);
                acc[1][1] = MFMA(a1, bh1, acc[1][1]);
                acc[1][1] = MFMA(a1, bl1, acc[1][1]);
            }
        }
        const int quad = lane >> 4;
        #pragma unroll
        for (int i = 0; i < 2; ++i) {
            #pragma unroll
            for (int j = 0; j < 2; ++j) {
                const int col = ct * 64 + wc * 32 + j * 16 + l15;
                const int m0  = rt * 64 + wr * 32 + i * 16 + quad * 4;
                const size_t base = (size_t)(b * 256 + m0) * 256 + col;
                #pragma unroll
                for (int r = 0; r < 4; ++r) {
                    ushort hi, lo;
                    split2(acc[i][j][r], hi, lo);
                    Yhi[base + (size_t)r * 256] = hi;
                    Ylo[base + (size_t)r * 256] = lo;
                }
            }
        }
    } else if (bid < mainB + 32) {
        if (p.doX)
            x_job(bid - mainB, tid, (float*)lds, (float*)(lds + 64 * LSTR),
                  p.Af, p.x2d, p.mask, p.Ax0, p.t);
    } else {
        if (p.headT >= 0)
            head_job(bid - mainB - 32, tid, p.h1, p.Wout, p.bout, p.out, p.headT);
    }
}

// ---------------------------------------------------------------------------
// wact body (verified GEMM + epilogue), shared by K4 kernel and karb z-blocks
// ---------------------------------------------------------------------------
struct WSub {
    const ushort* Lhi0; const ushort* Llo0; const ushort* RT0;
    const ushort* Lhi1; const ushort* Llo1; const ushort* RT1;
    int ngemm;
    const float* bias;
    int useK6; int wxColOff;
    const float* h;
    float* z;
    float* hOut;
    ushort* Thi; ushort* Tlo;
};

__device__ void wact_body(int b, int rt, int ct, int tid, ushort* lds,
                          const WSub& u, int mode, const float* Ax0,
                          const float* Wx0) {
    ushort* Ashi = lds;
    ushort* Aslo = lds + 64 * LSTR;
    ushort* Bs   = lds + 2 * 64 * LSTR;

    const int lane = tid & 63, wave = tid >> 6;
    const int wr = wave >> 1, wc = wave & 1;
    const int l15 = lane & 15, q8 = (lane >> 4) << 3;

    f32x4 acc[2][2];
    acc[0][0] = 0.f; acc[0][1] = 0.f; acc[1][0] = 0.f; acc[1][1] = 0.f;

    const int rr = tid >> 2, ko = (tid & 3) << 4;
    for (int g = 0; g < u.ngemm; ++g) {
        const ushort* Lh = (g ? u.Lhi1 : u.Lhi0) + (size_t)(b * 256 + rt * 64 + rr) * 256 + ko;
        const ushort* Ll = (g ? u.Llo1 : u.Llo0) + (size_t)(b * 256 + rt * 64 + rr) * 256 + ko;
        const ushort* Rt = (g ? u.RT1  : u.RT0 ) + (size_t)(ct * 64 + rr) * 256 + ko;
        ushort* wA = &Ashi[rr * LSTR + ko];
        ushort* wL = &Aslo[rr * LSTR + ko];
        ushort* wB = &Bs[rr * LSTR + ko];

        uint4 rA0 = *(const uint4*)(Lh);
        uint4 rA1 = *(const uint4*)(Lh + 8);
        uint4 rL0 = *(const uint4*)(Ll);
        uint4 rL1 = *(const uint4*)(Ll + 8);
        uint4 rB0 = *(const uint4*)(Rt);
        uint4 rB1 = *(const uint4*)(Rt + 8);

        for (int k0 = 0; k0 < 256; k0 += 64) {
            __syncthreads();
            *(uint4*)(wA)     = rA0;
            *(uint4*)(wA + 8) = rA1;
            *(uint4*)(wL)     = rL0;
            *(uint4*)(wL + 8) = rL1;
            *(uint4*)(wB)     = rB0;
            *(uint4*)(wB + 8) = rB1;
            __syncthreads();
            if (k0 < 192) {
                rA0 = *(const uint4*)(Lh + k0 + 64);
                rA1 = *(const uint4*)(Lh + k0 + 72);
                rL0 = *(const uint4*)(Ll + k0 + 64);
                rL1 = *(const uint4*)(Ll + k0 + 72);
                rB0 = *(const uint4*)(Rt + k0 + 64);
                rB1 = *(const uint4*)(Rt + k0 + 72);
            }
            #pragma unroll
            for (int sub = 0; sub < 2; ++sub) {
                const int kb = sub * 32 + q8;
                s16x8 ah0 = *(const s16x8*)&Ashi[(wr * 32 + l15) * LSTR + kb];
                s16x8 ah1 = *(const s16x8*)&Ashi[(wr * 32 + 16 + l15) * LSTR + kb];
                s16x8 al0 = *(const s16x8*)&Aslo[(wr * 32 + l15) * LSTR + kb];
                s16x8 al1 = *(const s16x8*)&Aslo[(wr * 32 + 16 + l15) * LSTR + kb];
                s16x8 b0  = *(const s16x8*)&Bs[(wc * 32 + l15) * LSTR + kb];
                s16x8 b1  = *(const s16x8*)&Bs[(wc * 32 + 16 + l15) * LSTR + kb];
                acc[0][0] = MFMA(ah0, b0, acc[0][0]);
                acc[0][0] = MFMA(al0, b0, acc[0][0]);
                acc[0][1] = MFMA(ah0, b1, acc[0][1]);
                acc[0][1] = MFMA(al0, b1, acc[0][1]);
                acc[1][0] = MFMA(ah1, b0, acc[1][0]);
                acc[1][0] = MFMA(al1, b0, acc[1][0]);
                acc[1][1] = MFMA(ah1, b1, acc[1][1]);
                acc[1][1] = MFMA(al1, b1, acc[1][1]);
            }
        }
    }

    const int quad = lane >> 4;
    const int m0base = rt * 64 + wr * 32;
    int colg[2];
    #pragma unroll
    for (int j = 0; j < 2; ++j) colg[j] = ct * 64 + wc * 32 + j * 16 + l15;
    float bv[2] = { u.bias[colg[0]], u.bias[colg[1]] };
    float v[2][2][4];
    #pragma unroll
    for (int i = 0; i < 2; ++i)
        #pragma unroll
        for (int j = 0; j < 2; ++j)
            #pragma unroll
            for (int r = 0; r < 4; ++r)
                v[i][j][r] = acc[i][j][r] + bv[j];

    if (u.useK6) {
        float w6[2][6];
        #pragma unroll
        for (int j = 0; j < 2; ++j)
            #pragma unroll
            for (int d = 0; d < 6; ++d)
                w6[j][d] = Wx0[d * 768 + u.wxColOff + colg[j]];
        #pragma unroll
        for (int i = 0; i < 2; ++i) {
            #pragma unroll
            for (int r = 0; r < 4; ++r) {
                int row = b * 256 + m0base + i * 16 + quad * 4 + r;
                const float* ax = Ax0 + (size_t)row * 8;
                float a0 = ax[0], a1 = ax[1], a2 = ax[2], a3 = ax[3], a4 = ax[4], a5 = ax[5];
                #pragma unroll
                for (int j = 0; j < 2; ++j)
                    v[i][j][r] += a0 * w6[j][0] + a1 * w6[j][1] + a2 * w6[j][2]
                                + a3 * w6[j][3] + a4 * w6[j][4] + a5 * w6[j][5];
            }
        }
    }

    if (mode == 0) {
        // z-gate only (rh handled by the fused rh_job now)
        #pragma unroll
        for (int i = 0; i < 2; ++i)
            #pragma unroll
            for (int r = 0; r < 4; ++r) {
                int row = b * 256 + m0base + i * 16 + quad * 4 + r;
                #pragma unroll
                for (int j = 0; j < 2; ++j)
                    u.z[(size_t)row * 256 + colg[j]] = 1.f / (1.f + __expf(-v[i][j][r]));
            }
    } else {
        #pragma unroll
        for (int i = 0; i < 2; ++i) {
            int m0 = m0base + i * 16 + quad * 4;
            #pragma unroll
            for (int j = 0; j < 2; ++j) {
                ushort hi4[4], lo4[4];
                #pragma unroll
                for (int r = 0; r < 4; ++r) {
                    int row = b * 256 + m0 + r;
                    size_t gi = (size_t)row * 256 + colg[j];
                    float c = tanhf(v[i][j][r]);
                    float zz = u.z[gi];
                    float hh = u.h[gi];
                    float hn = zz * hh + (1.f - zz) * c;
                    u.hOut[gi] = hn;
                    split2(hn, hi4[r], lo4[r]);
                }
                size_t off = (size_t)b * 65536 + (size_t)colg[j] * 256 + m0;
                *(ushort4*)&u.Thi[off] = make_ushort4(hi4[0], hi4[1], hi4[2], hi4[3]);
                *(ushort4*)&u.Tlo[off] = make_ushort4(lo4[0], lo4[1], lo4[2], lo4[3]);
            }
        }
    }
}

struct WAP2 {
    WSub u0, u1;
    int nBlk0;
    int mode;
    const float* Ax0; const float* Wx0;
};

__global__ __launch_bounds__(256) void wact_kernel(WAP2 p) {
    __shared__ ushort lds[3 * 64 * LSTR];
    const int tid = threadIdx.x;
    const int bid = blockIdx.x;
    const int isU1 = (bid >= p.nBlk0);
    const WSub u = isU1 ? p.u1 : p.u0;
    const int lb = isU1 ? bid - p.nBlk0 : bid;
    int b, rt, ct;
    if (p.mode == 0) { b = lb >> 5; rt = (lb >> 3) & 3; ct = lb & 7; }
    else             { b = lb >> 4; rt = (lb >> 2) & 3; ct = lb & 3; }
    wact_body(b, rt, ct, tid, lds, u, p.mode, p.Ax0, p.Wx0);
}

// ---------------------------------------------------------------------------
// karb: fused K2+K3. z-blocks (verified orientation) + rh-fused blocks:
// rh^T[32 f][256 m] = sigma(Wzr_r^T @ AH^T + bias + xfeed) * h^T  -> LDS
// ARH[256 n][32 f] = Abf @ rh^T  -> global split pair
// ---------------------------------------------------------------------------
struct KP2 {
    const ushort* Abf;
    const ushort* AH0hi; const ushort* AH0lo;
    const ushort* AH1hi; const ushort* AH1lo;
    const ushort* WzrT0; const ushort* WxzrT1; const ushort* WhzrT1;
    const float* b0; const float* b1;
    const float* Ax0; const float* Wx0;
    const ushort* h0Thi; const ushort* h0Tlo;
    const ushort* h1Thi; const ushort* h1Tlo;
    float* z0; float* z1;
    ushort* ARH0hi; ushort* ARH0lo;
    ushort* ARH1hi; ushort* ARH1lo;
    int L0; int L1;
};

#define CS 72     // WT chunk stride (ushorts)
#define RS 264    // rh^T LDS stride (ushorts)

__device__ void rh_job(int ell, int b, int fp, int tid, ushort* lds, const KP2& q) {
    ushort* WTa  = lds;                 // [32][CS]
    ushort* WTb  = lds + 32 * CS;       // [32][CS] (ell==1)
    ushort* rhHi = lds + 2 * 32 * CS;   // [32][RS]
    ushort* rhLo = rhHi + 32 * RS;

    const int F0 = fp * 32;
    const ushort* WT0 = ell ? q.WxzrT1 : q.WzrT0;
    const ushort* WT1 = q.WhzrT1;
    const ushort* B0h = q.AH0hi; const ushort* B0l = q.AH0lo;
    const ushort* B1h = q.AH1hi; const ushort* B1l = q.AH1lo;
    const float*  bias = ell ? q.b1 : q.b0;
    const ushort* hThi = ell ? q.h1Thi : q.h0Thi;
    const ushort* hTlo = ell ? q.h1Tlo : q.h0Tlo;
    ushort* Yhi = ell ? q.ARH1hi : q.ARH0hi;
    ushort* Ylo = ell ? q.ARH1lo : q.ARH0lo;

    const int lane = tid & 63, wave = tid >> 6;
    const int l15 = lane & 15, q8 = (lane >> 4) << 3, quad = lane >> 4;

    // -------- Phase A: zrpre^T -> rh^T into LDS --------------------------
    f32x4 acc[2][2][2];   // [msub][i][j]
    #pragma unroll
    for (int a = 0; a < 2; ++a)
        #pragma unroll
        for (int i = 0; i < 2; ++i)
            #pragma unroll
            for (int j = 0; j < 2; ++j) acc[a][i][j] = 0.f;

    const int srow = tid >> 3, skoff = (tid & 7) << 3;   // 32 rows x 8 uint4
    for (int k0 = 0; k0 < 256; k0 += 64) {
        __syncthreads();
        *(uint4*)&WTa[srow * CS + skoff] =
            *(const uint4*)&WT0[(size_t)(256 + F0 + srow) * 256 + k0 + skoff];
        if (ell)
            *(uint4*)&WTb[srow * CS + skoff] =
                *(const uint4*)&WT1[(size_t)(256 + F0 + srow) * 256 + k0 + skoff];
        __syncthreads();
        #pragma unroll
        for (int msub = 0; msub < 2; ++msub) {
            const int m0 = wave * 64 + msub * 32;
            const size_t gb0 = (size_t)(b * 256 + m0 + l15) * 256 + k0;
            const size_t gb1 = (size_t)(b * 256 + m0 + 16 + l15) * 256 + k0;
            #pragma unroll
            for (int sub = 0; sub < 2; ++sub) {
                const int kb = sub * 32 + q8;
                s16x8 a0 = *(const s16x8*)&WTa[l15 * CS + kb];
                s16x8 a1 = *(const s16x8*)&WTa[(16 + l15) * CS + kb];
                s16x8 bh0 = *(const s16x8*)&B0h[gb0 + kb];
                s16x8 bh1 = *(const s16x8*)&B0h[gb1 + kb];
                s16x8 bl0 = *(const s16x8*)&B0l[gb0 + kb];
                s16x8 bl1 = *(const s16x8*)&B0l[gb1 + kb];
                acc[msub][0][0] = MFMA(a0, bh0, acc[msub][0][0]);
                acc[msub][0][0] = MFMA(a0, bl0, acc[msub][0][0]);
                acc[msub][0][1] = MFMA(a0, bh1, acc[msub][0][1]);
                acc[msub][0][1] = MFMA(a0, bl1, acc[msub][0][1]);
                acc[msub][1][0] = MFMA(a1, bh0, acc[msub][1][0]);
                acc[msub][1][0] = MFMA(a1, bl0, acc[msub][1][0]);
                acc[msub][1][1] = MFMA(a1, bh1, acc[msub][1][1]);
                acc[msub][1][1] = MFMA(a1, bl1, acc[msub][1][1]);
                if (ell) {
                    s16x8 c0 = *(const s16x8*)&WTb[l15 * CS + kb];
                    s16x8 c1 = *(const s16x8*)&WTb[(16 + l15) * CS + kb];
                    s16x8 dh0 = *(const s16x8*)&B1h[gb0 + kb];
                    s16x8 dh1 = *(const s16x8*)&B1h[gb1 + kb];
                    s16x8 dl0 = *(const s16x8*)&B1l[gb0 + kb];
                    s16x8 dl1 = *(const s16x8*)&B1l[gb1 + kb];
                    acc[msub][0][0] = MFMA(c0, dh0, acc[msub][0][0]);
                    acc[msub][0][0] = MFMA(c0, dl0, acc[msub][0][0]);
                    acc[msub][0][1] = MFMA(c0, dh1, acc[msub][0][1]);
                    acc[msub][0][1] = MFMA(c0, dl1, acc[msub][0][1]);
                    acc[msub][1][0] = MFMA(c1, dh0, acc[msub][1][0]);
                    acc[msub][1][0] = MFMA(c1, dl0, acc[msub][1][0]);
                    acc[msub][1][1] = MFMA(c1, dh1, acc[msub][1][1]);
                    acc[msub][1][1] = MFMA(c1, dl1, acc[msub][1][1]);
                }
            }
        }
    }

    // epilogue: bias + xfeed(ell0) + sigmoid, * h^T (pair-reconstructed), split
    float w6[2][4][6];
    if (!ell) {
        #pragma unroll
        for (int i = 0; i < 2; ++i)
            #pragma unroll
            for (int r = 0; r < 4; ++r) {
                const int f = i * 16 + quad * 4 + r;
                #pragma unroll
                for (int d = 0; d < 6; ++d)
                    w6[i][r][d] = q.Wx0[d * 768 + 256 + F0 + f];
            }
    }
    #pragma unroll
    for (int msub = 0; msub < 2; ++msub) {
        #pragma unroll
        for (int j = 0; j < 2; ++j) {
            const int m = wave * 64 + msub * 32 + j * 16 + l15;
            float ax[6];
            if (!ell) {
                const float* axp = q.Ax0 + (size_t)(b * 256 + m) * 8;
                #pragma unroll
                for (int d = 0; d < 6; ++d) ax[d] = axp[d];
            }
            #pragma unroll
            for (int i = 0; i < 2; ++i)
                #pragma unroll
                for (int r = 0; r < 4; ++r) {
                    const int f = i * 16 + quad * 4 + r;
                    float v = acc[msub][i][j][r] + bias[256 + F0 + f];
                    if (!ell)
                        v += ax[0] * w6[i][r][0] + ax[1] * w6[i][r][1]
                           + ax[2] * w6[i][r][2] + ax[3] * w6[i][r][3]
                           + ax[4] * w6[i][r][4] + ax[5] * w6[i][r][5];
                    float rr = 1.f / (1.f + __expf(-v));
                    const size_t hoff = (size_t)b * 65536 + (size_t)(F0 + f) * 256 + m;
                    float hv = bf16_f32(hThi[hoff]) + bf16_f32(hTlo[hoff]);
                    ushort hi, lo;
                    split2(rr * hv, hi, lo);
                    rhHi[f * RS + m] = hi;
                    rhLo[f * RS + m] = lo;
                }
        }
    }
    __syncthreads();

    // -------- Phase B: ARH[256 n][32 f] = Abf @ rh^T ---------------------
    f32x4 acc2[4][2];
    #pragma unroll
    for (int i = 0; i < 4; ++i) { acc2[i][0] = 0.f; acc2[i][1] = 0.f; }
    const int n0 = wave * 64;
    for (int mc = 0; mc < 256; mc += 32) {
        const int kb = mc + q8;
        s16x8 a0 = *(const s16x8*)&q.Abf[(size_t)(n0 +      l15) * 256 + kb];
        s16x8 a1 = *(const s16x8*)&q.Abf[(size_t)(n0 + 16 + l15) * 256 + kb];
        s16x8 a2 = *(const s16x8*)&q.Abf[(size_t)(n0 + 32 + l15) * 256 + kb];
        s16x8 a3 = *(const s16x8*)&q.Abf[(size_t)(n0 + 48 + l15) * 256 + kb];
        s16x8 bh0 = *(const s16x8*)&rhHi[l15 * RS + kb];
        s16x8 bh1 = *(const s16x8*)&rhHi[(16 + l15) * RS + kb];
        s16x8 bl0 = *(const s16x8*)&rhLo[l15 * RS + kb];
        s16x8 bl1 = *(const s16x8*)&rhLo[(16 + l15) * RS + kb];
        acc2[0][0] = MFMA(a0, bh0, acc2[0][0]); acc2[0][0] = MFMA(a0, bl0, acc2[0][0]);
        acc2[0][1] = MFMA(a0, bh1, acc2[0][1]); acc2[0][1] = MFMA(a0, bl1, acc2[0][1]);
        acc2[1][0] = MFMA(a1, bh0, acc2[1][0]); acc2[1][0] = MFMA(a1, bl0, acc2[1][0]);
        acc2[1][1] = MFMA(a1, bh1, acc2[1][1]); acc2[1][1] = MFMA(a1, bl1, acc2[1][1]);
        acc2[2][0] = MFMA(a2, bh0, acc2[2][0]); acc2[2][0] = MFMA(a2, bl0, acc2[2][0]);
        acc2[2][1] = MFMA(a2, bh1, acc2[2][1]); acc2[2][1] = MFMA(a2, bl1, acc2[2][1]);
        acc2[3][0] = MFMA(a3, bh0, acc2[3][0]); acc2[3][0] = MFMA(a3, bl0, acc2[3][0]);
        acc2[3][1] = MFMA(a3, bh1, acc2[3][1]); acc2[3][1] = MFMA(a3, bl1, acc2[3][1]);
    }
    #pragma unroll
    for (int i = 0; i < 4; ++i) {
        #pragma unroll
        for (int j = 0; j < 2; ++j) {
            const int n = n0 + i * 16 + quad * 4;
            const int col = F0 + j * 16 + l15;
            const size_t base = (size_t)(b * 256 + n) * 256 + col;
            #pragma unroll
            for (int r = 0; r < 4; ++r) {
                ushort hi, lo;
                split2(acc2[i][j][r], hi, lo);
                Yhi[base + (size_t)r * 256] = hi;
                Ylo[base + (size_t)r * 256] = lo;
            }
        }
    }
}

__global__ __launch_bounds__(256) void karb_kernel(KP2 q) {
    __shared__ ushort lds[2 * 32 * CS + 2 * 32 * RS];   // 43008 B
    const int bid = blockIdx.x, tid = threadIdx.x;
    if (bid < 256) {
        const int ell = bid >> 7, lb = bid & 127;
        if (ell ? !q.L1 : !q.L0) return;
        const int b = lb >> 4, rt = (lb >> 2) & 3, ct = lb & 3;   // z cols only
        WSub u;
        if (ell) u = WSub{q.AH0hi, q.AH0lo, q.WxzrT1, q.AH1hi, q.AH1lo, q.WhzrT1,
                          2, q.b1, 0, 0, nullptr, q.z1, nullptr, nullptr, nullptr};
        else     u = WSub{q.AH0hi, q.AH0lo, q.WzrT0, nullptr, nullptr, nullptr,
                          1, q.b0, 1, 0, nullptr, q.z0, nullptr, nullptr, nullptr};
        wact_body(b, rt, ct, tid, lds, u, 0, q.Ax0, q.Wx0);
    } else {
        const int idx = bid - 256;
        const int ell = idx >> 6;
        if (ell ? !q.L1 : !q.L0) return;
        const int b = (idx >> 3) & 7, fp = idx & 7;
        rh_job(ell, b, fp, tid, lds, q);
    }
}

// ---------------------------------------------------------------------------
extern "C" void kernel_launch(void* const* d_in, const int* in_sizes, int n_in,
                              void* d_out, int out_size, void* d_ws, size_t ws_size,
                              hipStream_t stream) {
    const float* x2d  = (const float*)d_in[0];
    const float* mask = (const float*)d_in[1];
    const float* A    = (const float*)d_in[2];
    const float* Wx0  = (const float*)d_in[3];
    const float* Wh0  = (const float*)d_in[4];
    const float* b0   = (const float*)d_in[5];
    const float* Wx1  = (const float*)d_in[6];
    const float* Wh1  = (const float*)d_in[7];
    const float* b1   = (const float*)d_in[8];
    const float* Wout = (const float*)d_in[9];
    const float* bout = (const float*)d_in[10];
    float* out = (float*)d_out;

    const size_t SZ = (size_t)BN * HH;   // 524288
    float* ws = (float*)d_ws;
    float*  h0    = ws;
    float*  h1    = h0 + SZ;
    ushort* h0Thi = (ushort*)(h1 + SZ);
    ushort* h0Tlo = h0Thi + SZ;
    ushort* h1Thi = h0Tlo + SZ;
    ushort* h1Tlo = h1Thi + SZ;
    float*  z0    = (float*)(h1Tlo + SZ);
    float*  z1    = z0 + SZ;
    float*  Ax0   = z1 + SZ;             // 16384 f
    ushort* AH0hi = (ushort*)(Ax0 + 16384);
    ushort* AH0lo = AH0hi + SZ;
    ushort* AH1hi = AH0lo + SZ;          // pure AH1 now (no aliasing)
    ushort* AH1lo = AH1hi + SZ;
    ushort* ARH1hi= AH1lo + SZ;
    ushort* ARH1lo= ARH1hi + SZ;
    ushort* ARH0hi= ARH1lo + SZ;         // was RH0Thi (rhT now stays in LDS)
    ushort* ARH0lo= ARH0hi + SZ;
    ushort* unus1 = ARH0lo + SZ;         // was RH1T, unused
    ushort* unus2 = unus1 + SZ;
    ushort* Abf   = unus2 + SZ;          // 65536
    ushort* WzrT0 = Abf + 65536;         // 131072
    ushort* WcT0  = WzrT0 + 131072;      // 65536
    ushort* WxzrT1= WcT0 + 65536;        // 131072
    ushort* WhzrT1= WxzrT1 + 131072;     // 131072
    ushort* WxcT1 = WhzrT1 + 131072;     // 65536
    ushort* WhcT1 = WxcT1 + 65536;       // 65536

    // zero h0,h1 (fp32) and the four transposed split buffers (bf16 zero = 0)
    hipMemsetAsync(h0, 0, (2 * SZ) * sizeof(float) + 4 * SZ * sizeof(ushort), stream);

    prep_kernel<<<dim3(2560), dim3(256), 0, stream>>>(A, Wh0, Wx1, Wh1,
        Abf, WzrT0, WcT0, WxzrT1, WhzrT1, WxcT1, WhcT1);

    for (int s = 0; s <= TT; ++s) {
        const int L0 = (s < TT);
        const int L1 = (s >= 1);

        // K1: AH0 = A@h0T, AH1 = A@h1T (+ x_job(t=s), head(t=s-2))
        { G2P p{Abf, h0Thi, h0Tlo, AH0hi, AH0lo, h1Thi, h1Tlo, AH1hi, AH1lo,
                2, L0, (s >= 2 ? s - 2 : -1), s,
                A, x2d, mask, Ax0, h1, Wout, bout, out};
          g2_kernel<<<dim3(360), dim3(256), 0, stream>>>(p); }

        // K2+K3 fused: z gates + (r -> rh^T -> ARH) for both layers
        { KP2 q;
          q.Abf = Abf;
          q.AH0hi = AH0hi; q.AH0lo = AH0lo; q.AH1hi = AH1hi; q.AH1lo = AH1lo;
          q.WzrT0 = WzrT0; q.WxzrT1 = WxzrT1; q.WhzrT1 = WhzrT1;
          q.b0 = b0; q.b1 = b1; q.Ax0 = Ax0; q.Wx0 = Wx0;
          q.h0Thi = h0Thi; q.h0Tlo = h0Tlo; q.h1Thi = h1Thi; q.h1Tlo = h1Tlo;
          q.z0 = z0; q.z1 = z1;
          q.ARH0hi = ARH0hi; q.ARH0lo = ARH0lo;
          q.ARH1hi = ARH1hi; q.ARH1lo = ARH1lo;
          q.L0 = L0; q.L1 = L1;
          karb_kernel<<<dim3(384), dim3(256), 0, stream>>>(q); }

        // K4: c gate + state update — layer0 (h0, h0T) and layer1 (h1, h1T)
        { WAP2 p;
          p.u0 = WSub{ARH0hi, ARH0lo, WcT0, nullptr, nullptr, nullptr, 1,
                      b0 + 512, 1, 512, h0, z0, h0, h0Thi, h0Tlo};
          p.u1 = WSub{ARH1hi, ARH1lo, WhcT1, AH0hi, AH0lo, WxcT1, 2,
                      b1 + 512, 0, 0, h1, z1, h1, h1Thi, h1Tlo};
          p.mode = 1; p.Ax0 = Ax0; p.Wx0 = Wx0;
          int g;
          if (L0 && L1) { p.nBlk0 = 128; g = 256; }
          else if (L0)  { p.nBlk0 = 128; g = 128; }
          else          { p.nBlk0 = 0;   g = 128; }
          wact_kernel<<<dim3(g), dim3(256), 0, stream>>>(p); }
    }

    // final head for t = 63
    head_kernel<<<dim3(72), dim3(256), 0, stream>>>(h1, Wout, bout, out, TT - 1);
}

// Round 11
// 3300.880 us; speedup vs baseline: 1.2025x; 1.2025x over previous
//
#include <hip/hip_runtime.h>
#include <math.h>

// Round 11: lock in the session's best verified kernel (= Round 8, 3299 us).
// Multi-kernel 2-layer-pipelined schedule (3+1 kernels per super-step) with
// register double-buffered global->LDS staging in both GEMM kernels.
// Measured landscape: persistent-kernel barriers are correct only with full
// agent fences (9-29 ms; sc-bypass coherence falsified on gfx950, R4-R7);
// K2/K3 transposed fusion regressed to 3969 us (unstaged operand reads cost
// more than the dispatch gap saved, R10). This structure is the measured
// optimum: 5215 -> 3299 us over the session.

#define BB 8
#define TT 64
#define NN 256
#define HH 256
#define BN 2048
#define LSTR 72   // LDS row stride in ushorts for a 64-wide K chunk

typedef float f32x4 __attribute__((ext_vector_type(4)));
typedef short s16x8 __attribute__((ext_vector_type(8)));

#define MFMA(a, b, c) __builtin_amdgcn_mfma_f32_16x16x32_bf16(a, b, c, 0, 0, 0)

__device__ __forceinline__ ushort rne_bf16(float x) {
    unsigned u = __builtin_bit_cast(unsigned, x);
    unsigned r = u + 0x7FFFu + ((u >> 16) & 1u);
    return (ushort)(r >> 16);
}
__device__ __forceinline__ float bf16_f32(ushort h) {
    unsigned u = ((unsigned)h) << 16;
    return __builtin_bit_cast(float, u);
}
__device__ __forceinline__ void split2(float x, ushort& hi, ushort& lo) {
    ushort h = rne_bf16(x);
    hi = h;
    lo = rne_bf16(x - bf16_f32(h));
}

// ---------------------------------------------------------------------------
// prep: round A to bf16; build transposed bf16 weight slabs [Ncols][256]
// ---------------------------------------------------------------------------
__global__ __launch_bounds__(256) void prep_kernel(const float* __restrict__ A,
    const float* __restrict__ Wh0, const float* __restrict__ Wx1,
    const float* __restrict__ Wh1,
    ushort* Abf, ushort* WzrT0, ushort* WcT0, ushort* WxzrT1,
    ushort* WhzrT1, ushort* WxcT1, ushort* WhcT1)
{
    int idx = blockIdx.x * 256 + threadIdx.x;
    if (idx < 65536) { Abf[idx] = rne_bf16(A[idx]); return; }
    int e = idx - 65536;
    ushort* dst; const float* src; int colOff;
    if      (e < 131072) { dst = WzrT0;  src = Wh0; colOff = 0;   }
    else if (e < 196608) { dst = WcT0;   src = Wh0; colOff = 512; e -= 131072; }
    else if (e < 327680) { dst = WxzrT1; src = Wx1; colOff = 0;   e -= 196608; }
    else if (e < 458752) { dst = WhzrT1; src = Wh1; colOff = 0;   e -= 327680; }
    else if (e < 524288) { dst = WxcT1;  src = Wx1; colOff = 512; e -= 458752; }
    else if (e < 589824) { dst = WhcT1;  src = Wh1; colOff = 512; e -= 524288; }
    else return;
    int c = e >> 8, k = e & 255;
    dst[e] = rne_bf16(src[k * 768 + colOff + c]);
}

// ---------------------------------------------------------------------------
// device helpers: exact fp32 x-job (Ax0 = A@(x_t*mask)) and head
// ---------------------------------------------------------------------------
__device__ void x_job(int lb, int tid, float* xs, float* red, const float* Af,
                      const float* x2d, const float* mask, float* Ax0, int t) {
    int b = lb >> 2, rt = lb & 3;
    const float* xbase = x2d + ((size_t)(b * TT + t) * NN) * 6;
    const float* mbase = mask + (size_t)(b * TT + t) * NN;
    {
        int m = tid;
        float mk = mbase[m];
        #pragma unroll
        for (int d = 0; d < 6; ++d) xs[m * 8 + d] = xbase[m * 6 + d] * mk;
    }
    __syncthreads();
    int i = tid & 63, q = tid >> 6;
    const float* arow = Af + (size_t)(rt * 64 + i) * 256 + q * 64;
    float a6[6] = {0.f, 0.f, 0.f, 0.f, 0.f, 0.f};
    for (int m = 0; m < 64; ++m) {
        float a = arow[m];
        const float* xv = &xs[(q * 64 + m) * 8];
        #pragma unroll
        for (int d = 0; d < 6; ++d) a6[d] = fmaf(a, xv[d], a6[d]);
    }
    #pragma unroll
    for (int d = 0; d < 6; ++d) red[(i * 4 + q) * 8 + d] = a6[d];
    __syncthreads();
    for (int idx2 = tid; idx2 < 64 * 6; idx2 += 256) {
        int ii = idx2 / 6, d = idx2 - ii * 6;
        float s = red[(ii * 4 + 0) * 8 + d] + red[(ii * 4 + 1) * 8 + d]
                + red[(ii * 4 + 2) * 8 + d] + red[(ii * 4 + 3) * 8 + d];
        Ax0[(size_t)(b * 256 + rt * 64 + ii) * 8 + d] = s;
    }
}

__device__ void head_job(int lb, int tid, const float* h1, const float* Wout,
                         const float* bout, float* out, int tprev) {
    int g = lb * 256 + tid;
    int row = g / 9, o = g - row * 9;
    if (row >= BN) return;
    const float* hr = h1 + (size_t)row * 256;
    float s = bout[o];
    for (int k = 0; k < 256; k += 4) {
        float4 hv = *(const float4*)(hr + k);
        s = fmaf(hv.x, Wout[(k + 0) * 9 + o], s);
        s = fmaf(hv.y, Wout[(k + 1) * 9 + o], s);
        s = fmaf(hv.z, Wout[(k + 2) * 9 + o], s);
        s = fmaf(hv.w, Wout[(k + 3) * 9 + o], s);
    }
    int b = row >> 8, n = row & 255;
    out[((size_t)(b * TT + tprev) * NN + n) * 9 + o] = s;
}

__global__ __launch_bounds__(256) void head_kernel(const float* __restrict__ h1,
    const float* __restrict__ Wout, const float* __restrict__ bout,
    float* __restrict__ out, int tprev)
{
    head_job(blockIdx.x, threadIdx.x, h1, Wout, bout, out, tprev);
}

// ---------------------------------------------------------------------------
// g2: A-apply via MFMA.  Y(hi/lo split, [2048][256]) = A_bf16 @ XT(hi+lo)
// Register double-buffered staging: prefetch chunk k+1 after the post-write
// barrier so its global latency hides under chunk k's MFMAs.
// ---------------------------------------------------------------------------
struct G2P {
    const ushort* Abf;
    const ushort* XThi0; const ushort* XTlo0; ushort* Yhi0; ushort* Ylo0;
    const ushort* XThi1; const ushort* XTlo1; ushort* Yhi1; ushort* Ylo1;
    int nJobs;
    int doX;
    int headT;   // -1 = skip
    int t;
    const float* Af; const float* x2d; const float* mask; float* Ax0;
    const float* h1; const float* Wout; const float* bout; float* out;
};

__global__ __launch_bounds__(256) void g2_kernel(G2P p) {
    __shared__ ushort lds[3 * 64 * LSTR];
    ushort* As   = lds;
    ushort* Bshi = lds + 64 * LSTR;
    ushort* Bslo = lds + 2 * 64 * LSTR;
    const int tid = threadIdx.x;
    const int bid = blockIdx.x;
    const int mainB = p.nJobs * 128;

    if (bid < mainB) {
        const int job = bid >> 7, lb = bid & 127;
        const ushort* XThi = job ? p.XThi1 : p.XThi0;
        const ushort* XTlo = job ? p.XTlo1 : p.XTlo0;
        ushort* Yhi = job ? p.Yhi1 : p.Yhi0;
        ushort* Ylo = job ? p.Ylo1 : p.Ylo0;
        const int b = lb >> 4, rt = (lb >> 2) & 3, ct = lb & 3;

        const int lane = tid & 63, wave = tid >> 6;
        const int wr = wave >> 1, wc = wave & 1;
        const int l15 = lane & 15, q8 = (lane >> 4) << 3;

        f32x4 acc[2][2];
        acc[0][0] = 0.f; acc[0][1] = 0.f; acc[1][0] = 0.f; acc[1][1] = 0.f;

        const int rr = tid >> 2, ko = (tid & 3) << 4;
        const ushort* Asrc = p.Abf + (size_t)(rt * 64 + rr) * 256 + ko;
        const ushort* Bh   = XThi + (size_t)(b * 256 + ct * 64 + rr) * 256 + ko;
        const ushort* Bl   = XTlo + (size_t)(b * 256 + ct * 64 + rr) * 256 + ko;
        ushort* wA = &As[rr * LSTR + ko];
        ushort* wH = &Bshi[rr * LSTR + ko];
        ushort* wL = &Bslo[rr * LSTR + ko];

        // preload chunk 0 into registers
        uint4 rA0 = *(const uint4*)(Asrc);
        uint4 rA1 = *(const uint4*)(Asrc + 8);
        uint4 rH0 = *(const uint4*)(Bh);
        uint4 rH1 = *(const uint4*)(Bh + 8);
        uint4 rL0 = *(const uint4*)(Bl);
        uint4 rL1 = *(const uint4*)(Bl + 8);

        for (int k0 = 0; k0 < 256; k0 += 64) {
            __syncthreads();
            *(uint4*)(wA)     = rA0;
            *(uint4*)(wA + 8) = rA1;
            *(uint4*)(wH)     = rH0;
            *(uint4*)(wH + 8) = rH1;
            *(uint4*)(wL)     = rL0;
            *(uint4*)(wL + 8) = rL1;
            __syncthreads();
            if (k0 < 192) {   // prefetch next chunk; latency hides under MFMAs
                rA0 = *(const uint4*)(Asrc + k0 + 64);
                rA1 = *(const uint4*)(Asrc + k0 + 72);
                rH0 = *(const uint4*)(Bh + k0 + 64);
                rH1 = *(const uint4*)(Bh + k0 + 72);
                rL0 = *(const uint4*)(Bl + k0 + 64);
                rL1 = *(const uint4*)(Bl + k0 + 72);
            }
            #pragma unroll
            for (int sub = 0; sub < 2; ++sub) {
                const int kb = sub * 32 + q8;
                s16x8 a0  = *(const s16x8*)&As[(wr * 32 + l15) * LSTR + kb];
                s16x8 a1  = *(const s16x8*)&As[(wr * 32 + 16 + l15) * LSTR + kb];
                s16x8 bh0 = *(const s16x8*)&Bshi[(wc * 32 + l15) * LSTR + kb];
                s16x8 bh1 = *(const s16x8*)&Bshi[(wc * 32 + 16 + l15) * LSTR + kb];
                s16x8 bl0 = *(const s16x8*)&Bslo[(wc * 32 + l15) * LSTR + kb];
                s16x8 bl1 = *(const s16x8*)&Bslo[(wc * 32 + 16 + l15) * LSTR + kb];
                acc[0][0] = MFMA(a0, bh0, acc[0][0]);
                acc[0][0] = MFMA(a0, bl0, acc[0][0]);
                acc[0][1] = MFMA(a0, bh1, acc[0][1]);
                acc[0][1] = MFMA(a0, bl1, acc[0][1]);
                acc[1][0] = MFMA(a1, bh0, acc[1][0]);
                acc[1][0] = MFMA(a1, bl0, acc[1][0]);
                acc[1][1] = MFMA(a1, bh1, acc[1][1]);
                acc[1][1] = MFMA(a1, bl1, acc[1][1]);
            }
        }
        const int quad = lane >> 4;
        #pragma unroll
        for (int i = 0; i < 2; ++i) {
            #pragma unroll
            for (int j = 0; j < 2; ++j) {
                const int col = ct * 64 + wc * 32 + j * 16 + l15;
                const int m0  = rt * 64 + wr * 32 + i * 16 + quad * 4;
                const size_t base = (size_t)(b * 256 + m0) * 256 + col;
                #pragma unroll
                for (int r = 0; r < 4; ++r) {
                    ushort hi, lo;
                    split2(acc[i][j][r], hi, lo);
                    Yhi[base + (size_t)r * 256] = hi;
                    Ylo[base + (size_t)r * 256] = lo;
                }
            }
        }
    } else if (bid < mainB + 32) {
        if (p.doX)
            x_job(bid - mainB, tid, (float*)lds, (float*)(lds + 64 * LSTR),
                  p.Af, p.x2d, p.mask, p.Ax0, p.t);
    } else {
        if (p.headT >= 0)
            head_job(bid - mainB - 32, tid, p.h1, p.Wout, p.bout, p.out, p.headT);
    }
}

// ---------------------------------------------------------------------------
// wact: gate GEMM (left = dynamic split pair, right = static bf16 WT) + epilogue
// Two sub-dispatches (layer0 / layer1) selected by block id vs nBlk0.
// mode 0 (zr): 8 col-tiles; ct<4 -> z=sigmoid; ct>=4 -> rhT split pair
// mode 1 (c):  4 col-tiles; h' = z*h+(1-z)*tanh(g); writes h fp32 + hT pair
// ---------------------------------------------------------------------------
struct WSub {
    const ushort* Lhi0; const ushort* Llo0; const ushort* RT0;
    const ushort* Lhi1; const ushort* Llo1; const ushort* RT1;
    int ngemm;
    const float* bias;
    int useK6; int wxColOff;
    const float* h;
    float* z;
    float* hOut;
    ushort* Thi; ushort* Tlo;
};

struct WAP2 {
    WSub u0, u1;
    int nBlk0;
    int mode;
    const float* Ax0; const float* Wx0;
};

__global__ __launch_bounds__(256) void wact_kernel(WAP2 p) {
    __shared__ ushort lds[3 * 64 * LSTR];
    ushort* Ashi = lds;
    ushort* Aslo = lds + 64 * LSTR;
    ushort* Bs   = lds + 2 * 64 * LSTR;
    const int tid = threadIdx.x;
    const int bid = blockIdx.x;
    const int isU1 = (bid >= p.nBlk0);
    const WSub u = isU1 ? p.u1 : p.u0;
    const int lb = isU1 ? bid - p.nBlk0 : bid;
    int b, rt, ct;
    if (p.mode == 0) { b = lb >> 5; rt = (lb >> 3) & 3; ct = lb & 7; }
    else             { b = lb >> 4; rt = (lb >> 2) & 3; ct = lb & 3; }

    const int lane = tid & 63, wave = tid >> 6;
    const int wr = wave >> 1, wc = wave & 1;
    const int l15 = lane & 15, q8 = (lane >> 4) << 3;

    f32x4 acc[2][2];
    acc[0][0] = 0.f; acc[0][1] = 0.f; acc[1][0] = 0.f; acc[1][1] = 0.f;

    const int rr = tid >> 2, ko = (tid & 3) << 4;
    for (int g = 0; g < u.ngemm; ++g) {
        const ushort* Lh = (g ? u.Lhi1 : u.Lhi0) + (size_t)(b * 256 + rt * 64 + rr) * 256 + ko;
        const ushort* Ll = (g ? u.Llo1 : u.Llo0) + (size_t)(b * 256 + rt * 64 + rr) * 256 + ko;
        const ushort* Rt = (g ? u.RT1  : u.RT0 ) + (size_t)(ct * 64 + rr) * 256 + ko;
        ushort* wA = &Ashi[rr * LSTR + ko];
        ushort* wL = &Aslo[rr * LSTR + ko];
        ushort* wB = &Bs[rr * LSTR + ko];

        // preload chunk 0 of this gemm
        uint4 rA0 = *(const uint4*)(Lh);
        uint4 rA1 = *(const uint4*)(Lh + 8);
        uint4 rL0 = *(const uint4*)(Ll);
        uint4 rL1 = *(const uint4*)(Ll + 8);
        uint4 rB0 = *(const uint4*)(Rt);
        uint4 rB1 = *(const uint4*)(Rt + 8);

        for (int k0 = 0; k0 < 256; k0 += 64) {
            __syncthreads();
            *(uint4*)(wA)     = rA0;
            *(uint4*)(wA + 8) = rA1;
            *(uint4*)(wL)     = rL0;
            *(uint4*)(wL + 8) = rL1;
            *(uint4*)(wB)     = rB0;
            *(uint4*)(wB + 8) = rB1;
            __syncthreads();
            if (k0 < 192) {   // prefetch next chunk
                rA0 = *(const uint4*)(Lh + k0 + 64);
                rA1 = *(const uint4*)(Lh + k0 + 72);
                rL0 = *(const uint4*)(Ll + k0 + 64);
                rL1 = *(const uint4*)(Ll + k0 + 72);
                rB0 = *(const uint4*)(Rt + k0 + 64);
                rB1 = *(const uint4*)(Rt + k0 + 72);
            }
            #pragma unroll
            for (int sub = 0; sub < 2; ++sub) {
                const int kb = sub * 32 + q8;
                s16x8 ah0 = *(const s16x8*)&Ashi[(wr * 32 + l15) * LSTR + kb];
                s16x8 ah1 = *(const s16x8*)&Ashi[(wr * 32 + 16 + l15) * LSTR + kb];
                s16x8 al0 = *(const s16x8*)&Aslo[(wr * 32 + l15) * LSTR + kb];
                s16x8 al1 = *(const s16x8*)&Aslo[(wr * 32 + 16 + l15) * LSTR + kb];
                s16x8 b0  = *(const s16x8*)&Bs[(wc * 32 + l15) * LSTR + kb];
                s16x8 b1  = *(const s16x8*)&Bs[(wc * 32 + 16 + l15) * LSTR + kb];
                acc[0][0] = MFMA(ah0, b0, acc[0][0]);
                acc[0][0] = MFMA(al0, b0, acc[0][0]);
                acc[0][1] = MFMA(ah0, b1, acc[0][1]);
                acc[0][1] = MFMA(al0, b1, acc[0][1]);
                acc[1][0] = MFMA(ah1, b0, acc[1][0]);
                acc[1][0] = MFMA(al1, b0, acc[1][0]);
                acc[1][1] = MFMA(ah1, b1, acc[1][1]);
                acc[1][1] = MFMA(al1, b1, acc[1][1]);
            }
        }
    }

    const int quad = lane >> 4;
    const int m0base = rt * 64 + wr * 32;
    int colg[2];
    #pragma unroll
    for (int j = 0; j < 2; ++j) colg[j] = ct * 64 + wc * 32 + j * 16 + l15;
    float bv[2] = { u.bias[colg[0]], u.bias[colg[1]] };
    float v[2][2][4];
    #pragma unroll
    for (int i = 0; i < 2; ++i)
        #pragma unroll
        for (int j = 0; j < 2; ++j)
            #pragma unroll
            for (int r = 0; r < 4; ++r)
                v[i][j][r] = acc[i][j][r] + bv[j];

    if (u.useK6) {
        float w6[2][6];
        #pragma unroll
        for (int j = 0; j < 2; ++j)
            #pragma unroll
            for (int d = 0; d < 6; ++d)
                w6[j][d] = p.Wx0[d * 768 + u.wxColOff + colg[j]];
        #pragma unroll
        for (int i = 0; i < 2; ++i) {
            #pragma unroll
            for (int r = 0; r < 4; ++r) {
                int row = b * 256 + m0base + i * 16 + quad * 4 + r;
                const float* ax = p.Ax0 + (size_t)row * 8;
                float a0 = ax[0], a1 = ax[1], a2 = ax[2], a3 = ax[3], a4 = ax[4], a5 = ax[5];
                #pragma unroll
                for (int j = 0; j < 2; ++j)
                    v[i][j][r] += a0 * w6[j][0] + a1 * w6[j][1] + a2 * w6[j][2]
                                + a3 * w6[j][3] + a4 * w6[j][4] + a5 * w6[j][5];
            }
        }
    }

    if (p.mode == 0) {
        if (ct < 4) {
            #pragma unroll
            for (int i = 0; i < 2; ++i)
                #pragma unroll
                for (int r = 0; r < 4; ++r) {
                    int row = b * 256 + m0base + i * 16 + quad * 4 + r;
                    #pragma unroll
                    for (int j = 0; j < 2; ++j)
                        u.z[(size_t)row * 256 + colg[j]] = 1.f / (1.f + __expf(-v[i][j][r]));
                }
        } else {
            #pragma unroll
            for (int i = 0; i < 2; ++i) {
                int m0 = m0base + i * 16 + quad * 4;
                #pragma unroll
                for (int j = 0; j < 2; ++j) {
                    int colp = colg[j] - 256;
                    ushort hi4[4], lo4[4];
                    #pragma unroll
                    for (int r = 0; r < 4; ++r) {
                        int row = b * 256 + m0 + r;
                        float s = 1.f / (1.f + __expf(-v[i][j][r]));
                        float rh = s * u.h[(size_t)row * 256 + colp];
                        split2(rh, hi4[r], lo4[r]);
                    }
                    size_t off = (size_t)b * 65536 + (size_t)colp * 256 + m0;
                    *(ushort4*)&u.Thi[off] = make_ushort4(hi4[0], hi4[1], hi4[2], hi4[3]);
                    *(ushort4*)&u.Tlo[off] = make_ushort4(lo4[0], lo4[1], lo4[2], lo4[3]);
                }
            }
        }
    } else {
        #pragma unroll
        for (int i = 0; i < 2; ++i) {
            int m0 = m0base + i * 16 + quad * 4;
            #pragma unroll
            for (int j = 0; j < 2; ++j) {
                ushort hi4[4], lo4[4];
                #pragma unroll
                for (int r = 0; r < 4; ++r) {
                    int row = b * 256 + m0 + r;
                    size_t gi = (size_t)row * 256 + colg[j];
                    float c = tanhf(v[i][j][r]);
                    float zz = u.z[gi];
                    float hh = u.h[gi];
                    float hn = zz * hh + (1.f - zz) * c;
                    u.hOut[gi] = hn;
                    split2(hn, hi4[r], lo4[r]);
                }
                size_t off = (size_t)b * 65536 + (size_t)colg[j] * 256 + m0;
                *(ushort4*)&u.Thi[off] = make_ushort4(hi4[0], hi4[1], hi4[2], hi4[3]);
                *(ushort4*)&u.Tlo[off] = make_ushort4(lo4[0], lo4[1], lo4[2], lo4[3]);
            }
        }
    }
}

// ---------------------------------------------------------------------------
extern "C" void kernel_launch(void* const* d_in, const int* in_sizes, int n_in,
                              void* d_out, int out_size, void* d_ws, size_t ws_size,
                              hipStream_t stream) {
    const float* x2d  = (const float*)d_in[0];
    const float* mask = (const float*)d_in[1];
    const float* A    = (const float*)d_in[2];
    const float* Wx0  = (const float*)d_in[3];
    const float* Wh0  = (const float*)d_in[4];
    const float* b0   = (const float*)d_in[5];
    const float* Wx1  = (const float*)d_in[6];
    const float* Wh1  = (const float*)d_in[7];
    const float* b1   = (const float*)d_in[8];
    const float* Wout = (const float*)d_in[9];
    const float* bout = (const float*)d_in[10];
    float* out = (float*)d_out;

    const size_t SZ = (size_t)BN * HH;   // 524288
    float* ws = (float*)d_ws;
    float*  h0    = ws;
    float*  h1    = h0 + SZ;
    ushort* h0Thi = (ushort*)(h1 + SZ);
    ushort* h0Tlo = h0Thi + SZ;
    ushort* h1Thi = h0Tlo + SZ;
    ushort* h1Tlo = h1Thi + SZ;
    float*  z0    = (float*)(h1Tlo + SZ);
    float*  z1    = z0 + SZ;
    float*  Ax0   = z1 + SZ;             // 16384 f
    ushort* AH0hi = (ushort*)(Ax0 + 16384);   // A@h0(s-1) == Ax1 for layer1
    ushort* AH0lo = AH0hi + SZ;
    ushort* AH1hi = AH0lo + SZ;               // A@h1(s-2); reused as ARH0 after K2
    ushort* AH1lo = AH1hi + SZ;
    ushort* ARH1hi= AH1lo + SZ;
    ushort* ARH1lo= ARH1hi + SZ;
    ushort* RH0Thi= ARH1lo + SZ;
    ushort* RH0Tlo= RH0Thi + SZ;
    ushort* RH1Thi= RH0Tlo + SZ;
    ushort* RH1Tlo= RH1Thi + SZ;
    ushort* Abf   = RH1Tlo + SZ;         // 65536
    ushort* WzrT0 = Abf + 65536;         // 131072
    ushort* WcT0  = WzrT0 + 131072;      // 65536
    ushort* WxzrT1= WcT0 + 65536;        // 131072
    ushort* WhzrT1= WxzrT1 + 131072;     // 131072
    ushort* WxcT1 = WhzrT1 + 131072;     // 65536
    ushort* WhcT1 = WxcT1 + 65536;       // 65536
    // ARH0 aliases AH1: AH1 is last read in K2; ARH0 is written in K3.
    ushort* ARH0hi = AH1hi;
    ushort* ARH0lo = AH1lo;

    // zero h0,h1 (fp32) and the four transposed split buffers (bf16 zero = 0)
    hipMemsetAsync(h0, 0, (2 * SZ) * sizeof(float) + 4 * SZ * sizeof(ushort), stream);

    prep_kernel<<<dim3(2560), dim3(256), 0, stream>>>(A, Wh0, Wx1, Wh1,
        Abf, WzrT0, WcT0, WxzrT1, WhzrT1, WxcT1, WhcT1);

    // super-step s: layer0 at t=s (if s<64), layer1 at t=s-1 (if s>=1)
    for (int s = 0; s <= TT; ++s) {
        const int L0 = (s < TT);
        const int L1 = (s >= 1);

        // K1: AH0 = A@h0T, AH1 = A@h1T (+ x_job(t=s), head(t=s-2))
        { G2P p{Abf, h0Thi, h0Tlo, AH0hi, AH0lo, h1Thi, h1Tlo, AH1hi, AH1lo,
                2, L0, (s >= 2 ? s - 2 : -1), s,
                A, x2d, mask, Ax0, h1, Wout, bout, out};
          g2_kernel<<<dim3(360), dim3(256), 0, stream>>>(p); }

        // K2: zr gates — layer0 (z0, rh0T) and layer1 (z1, rh1T) combined
        { WAP2 p;
          p.u0 = WSub{AH0hi, AH0lo, WzrT0, nullptr, nullptr, nullptr, 1,
                      b0, 1, 0, h0, z0, nullptr, RH0Thi, RH0Tlo};
          p.u1 = WSub{AH0hi, AH0lo, WxzrT1, AH1hi, AH1lo, WhzrT1, 2,
                      b1, 0, 0, h1, z1, nullptr, RH1Thi, RH1Tlo};
          p.mode = 0; p.Ax0 = Ax0; p.Wx0 = Wx0;
          int g;
          if (L0 && L1) { p.nBlk0 = 256; g = 512; }
          else if (L0)  { p.nBlk0 = 256; g = 256; }
          else          { p.nBlk0 = 0;   g = 256; }
          wact_kernel<<<dim3(g), dim3(256), 0, stream>>>(p); }

        // K3: ARH0 = A@rh0T, ARH1 = A@rh1T
        { G2P p{Abf,
                L0 ? RH0Thi : RH1Thi, L0 ? RH0Tlo : RH1Tlo,
                L0 ? ARH0hi : ARH1hi, L0 ? ARH0lo : ARH1lo,
                RH1Thi, RH1Tlo, ARH1hi, ARH1lo,
                (L0 && L1) ? 2 : 1, 0, -1, s,
                A, x2d, mask, Ax0, h1, Wout, bout, out};
          g2_kernel<<<dim3(((L0 && L1) ? 2 : 1) * 128), dim3(256), 0, stream>>>(p); }

        // K4: c gate + state update — layer0 (h0, h0T) and layer1 (h1, h1T)
        { WAP2 p;
          p.u0 = WSub{ARH0hi, ARH0lo, WcT0, nullptr, nullptr, nullptr, 1,
                      b0 + 512, 1, 512, h0, z0, h0, h0Thi, h0Tlo};
          p.u1 = WSub{ARH1hi, ARH1lo, WhcT1, AH0hi, AH0lo, WxcT1, 2,
                      b1 + 512, 0, 0, h1, z1, h1, h1Thi, h1Tlo};
          p.mode = 1; p.Ax0 = Ax0; p.Wx0 = Wx0;
          int g;
          if (L0 && L1) { p.nBlk0 = 128; g = 256; }
          else if (L0)  { p.nBlk0 = 128; g = 128; }
          else          { p.nBlk0 = 0;   g = 128; }
          wact_kernel<<<dim3(g), dim3(256), 0, stream>>>(p); }
    }

    // final head for t = 63
    head_kernel<<<dim3(72), dim3(256), 0, stream>>>(h1, Wout, bout, out, TT - 1);
}